// Round 3
// baseline (5466.014 us; speedup 1.0000x reference)
//
#include <hip/hip_runtime.h>

// Triaffine: S[b,z,x,y] = sum_{i,j,k} xb[b,x,i] * W[i,k,j] * yb[b,y,j] * z[b,z,k]
//   xb = [x | 1] (i: 513), yb = [y | 1] (j: 513), k: 512
// K1: T2[bi,kk,x,y] = Xb * W_k * Yb^T   (fused two-GEMM per (b,k) block)
// K2: S[b,z,x,y]   += sum_k z[b,z,k] * T2[bi,kk,x,y]
// Chunked over (batch BC, k KC) so the T2 slab fits any ws_size >= 2.1 MB.

#define SEQ 128
#define DD  512
#define WI  262656   // i-stride in weight = 512*513
#define WK  513      // k-stride in weight

__device__ __forceinline__ float4 ld4(const float* p) { return *(const float4*)p; }

__global__ __launch_bounds__(256, 2)
void triaffine_k1(const float* __restrict__ X, const float* __restrict__ Y,
                  const float* __restrict__ W, float* __restrict__ T2,
                  int b0, int k0, int KC)
{
    const int bi  = blockIdx.x;        // local batch index within chunk
    const int b   = b0 + bi;
    const int kk  = blockIdx.y;
    const int k   = k0 + kk;
    const int tid = threadIdx.x;

    __shared__ __align__(16) float smem[14848];
    float* xT   = smem;            // [32][132]  x-chunk transposed: xT[ii][xx]
    float* wT   = smem + 4224;     // [32][68]   W-chunk: wT[ii][jj]
    float* yT   = smem;            // [32][132]  (aliases xT, phase B)
    float* gt   = smem + 6400;     // [64][132]  G tile: gt[jj][xx]
    float* wcol = smem;            // [513]      W[:,k,512]
    float* g512 = smem + 520;      // [2][128]

    const float* Xb = X + (size_t)b * SEQ * DD;
    const float* Yb = Y + (size_t)b * SEQ * DD;
    const float* Wk = W + (size_t)k * WK;

    const int xg = tid & 15;   // phase A: x-group (8 rows)
    const int jg = tid >> 4;   // phase A: j-group (4 cols)
    const int ty = tid >> 4;   // phase B: x-group (8 rows)
    const int tx = tid & 15;   // phase B: y-group (8 cols)

    float acc[8][8];
    #pragma unroll
    for (int a = 0; a < 8; ++a)
        #pragma unroll
        for (int c = 0; c < 8; ++c) acc[a][c] = 0.f;

    for (int jt = 0; jt < 512; jt += 64) {
        float greg[4][8];
        #pragma unroll
        for (int c = 0; c < 4; ++c)
            #pragma unroll
            for (int a = 0; a < 8; ++a) greg[c][a] = 0.f;

        for (int ic = 0; ic < 512; ic += 32) {
            __syncthreads();
            {   // load xT[ii][xx] = Xb[xx*512 + ic+ii]   (coalesced along i)
                const int ii = tid & 31, xs = tid >> 5;
                const float* src = Xb + (size_t)(xs * 16) * DD + ic + ii;
                #pragma unroll
                for (int r = 0; r < 16; ++r)
                    xT[ii * 132 + xs * 16 + r] = src[(size_t)r * DD];
            }
            {   // load wT[ii][jj] = W[ic+ii, k, jt+jj]   (coalesced along j)
                const int jj = tid & 63, iw = tid >> 6;
                #pragma unroll
                for (int r = 0; r < 8; ++r) {
                    const int ii = iw * 8 + r;
                    wT[ii * 68 + jj] = Wk[(size_t)(ic + ii) * WI + jt + jj];
                }
            }
            __syncthreads();
            #pragma unroll 8
            for (int ii = 0; ii < 32; ++ii) {
                const float4 wv  = ld4(&wT[ii * 68 + jg * 4]);
                const float4 xa  = ld4(&xT[ii * 132 + xg * 8]);
                const float4 xb2 = ld4(&xT[ii * 132 + xg * 8 + 4]);
                const float xs0[8] = {xa.x, xa.y, xa.z, xa.w, xb2.x, xb2.y, xb2.z, xb2.w};
                const float ws0[4] = {wv.x, wv.y, wv.z, wv.w};
                #pragma unroll
                for (int c = 0; c < 4; ++c)
                    #pragma unroll
                    for (int a = 0; a < 8; ++a)
                        greg[c][a] = fmaf(xs0[a], ws0[c], greg[c][a]);
            }
        }
        // i = 512 bias row of xb: += 1 * W[512, k, jt+jj]
        #pragma unroll
        for (int c = 0; c < 4; ++c) {
            const float w = Wk[(size_t)512 * WI + jt + jg * 4 + c];
            #pragma unroll
            for (int a = 0; a < 8; ++a) greg[c][a] += w;
        }
        __syncthreads();
        #pragma unroll
        for (int c = 0; c < 4; ++c) {
            float4 lo = make_float4(greg[c][0], greg[c][1], greg[c][2], greg[c][3]);
            float4 hi = make_float4(greg[c][4], greg[c][5], greg[c][6], greg[c][7]);
            *(float4*)&gt[(jg * 4 + c) * 132 + xg * 8]     = lo;
            *(float4*)&gt[(jg * 4 + c) * 132 + xg * 8 + 4] = hi;
        }
        for (int h = 0; h < 2; ++h) {
            __syncthreads();
            {   // load yT[jj2][yy] = Yb[yy*512 + jt + h*32 + jj2]
                const int ii = tid & 31, ys = tid >> 5;
                const float* src = Yb + (size_t)(ys * 16) * DD + jt + h * 32 + ii;
                #pragma unroll
                for (int r = 0; r < 16; ++r)
                    yT[ii * 132 + ys * 16 + r] = src[(size_t)r * DD];
            }
            __syncthreads();
            #pragma unroll 8
            for (int jj2 = 0; jj2 < 32; ++jj2) {
                const float4 ga  = ld4(&gt[(h * 32 + jj2) * 132 + ty * 8]);
                const float4 gb  = ld4(&gt[(h * 32 + jj2) * 132 + ty * 8 + 4]);
                const float4 ya  = ld4(&yT[jj2 * 132 + tx * 8]);
                const float4 yb4 = ld4(&yT[jj2 * 132 + tx * 8 + 4]);
                const float gr[8] = {ga.x, ga.y, ga.z, ga.w, gb.x, gb.y, gb.z, gb.w};
                const float yr[8] = {ya.x, ya.y, ya.z, ya.w, yb4.x, yb4.y, yb4.z, yb4.w};
                #pragma unroll
                for (int a = 0; a < 8; ++a)
                    #pragma unroll
                    for (int c = 0; c < 8; ++c)
                        acc[a][c] = fmaf(gr[a], yr[c], acc[a][c]);
            }
        }
    }
    // j = 512 bias column of yb: acc[x][*] += G[x,512], G[x,512] = sum_i xb[x,i] W[i,k,512]
    __syncthreads();
    for (int idx = tid; idx < 513; idx += 256)
        wcol[idx] = Wk[(size_t)idx * WI + 512];
    __syncthreads();
    {
        const int half = tid >> 7, xx = tid & 127;
        const float* xr = Xb + (size_t)xx * DD + half * 256;
        const float* wc = wcol + half * 256;
        float s = 0.f;
        #pragma unroll 8
        for (int r = 0; r < 64; ++r) {
            const float4 xv = ld4(&xr[r * 4]);
            s += xv.x * wc[r * 4] + xv.y * wc[r * 4 + 1] + xv.z * wc[r * 4 + 2] + xv.w * wc[r * 4 + 3];
        }
        g512[half * 128 + xx] = s;
    }
    __syncthreads();
    {
        const float wbb = wcol[512];   // bias-x * bias-y term
        #pragma unroll
        for (int a = 0; a < 8; ++a) {
            const float g = g512[ty * 8 + a] + g512[128 + ty * 8 + a] + wbb;
            #pragma unroll
            for (int c = 0; c < 8; ++c) acc[a][c] += g;
        }
    }
    // store T2[bi][kk][x][y]
    float* t2p = T2 + ((size_t)bi * KC + kk) * (SEQ * SEQ);
    #pragma unroll
    for (int a = 0; a < 8; ++a) {
        float4 lo = make_float4(acc[a][0], acc[a][1], acc[a][2], acc[a][3]);
        float4 hi = make_float4(acc[a][4], acc[a][5], acc[a][6], acc[a][7]);
        *(float4*)&t2p[(ty * 8 + a) * SEQ + tx * 8]     = lo;
        *(float4*)&t2p[(ty * 8 + a) * SEQ + tx * 8 + 4] = hi;
    }
}

__global__ __launch_bounds__(256, 2)
void triaffine_k2(const float* __restrict__ Z, const float* __restrict__ T2,
                  float* __restrict__ OUT, int b0, int k0, int KC, int first)
{
    const int nb  = blockIdx.x;       // n-tile over flattened (x,y): n0 = nb*128
    const int bi  = blockIdx.y;       // local batch index within chunk
    const int b   = b0 + bi;
    const int tid = threadIdx.x;
    const int tz  = tid >> 4, tn = tid & 15;
    const int n0  = nb * 128;

    __shared__ __align__(16) float zl[32 * 132];
    __shared__ __align__(16) float t2l[32 * 132];

    const float* Zb = Z + (size_t)b * SEQ * DD;

    float acc[8][8];
    #pragma unroll
    for (int a = 0; a < 8; ++a)
        #pragma unroll
        for (int c = 0; c < 8; ++c) acc[a][c] = 0.f;

    for (int kc = 0; kc < KC; kc += 32) {
        __syncthreads();
        {   // zl[ii][zz] = z[b, zz, k0+kc+ii]
            const int ii = tid & 31, zs = tid >> 5;
            const float* src = Zb + (size_t)(zs * 16) * DD + k0 + kc + ii;
            #pragma unroll
            for (int r = 0; r < 16; ++r)
                zl[ii * 132 + zs * 16 + r] = src[(size_t)r * DD];
        }
        {   // t2l[ii][nn] = T2[bi, kc+ii, n0+nn]
            const int nn = tid & 127, ih = tid >> 7;
            const float* src = T2 + ((size_t)bi * KC + kc + ih * 16) * 16384 + n0 + nn;
            #pragma unroll
            for (int r = 0; r < 16; ++r)
                t2l[(ih * 16 + r) * 132 + nn] = src[(size_t)r * 16384];
        }
        __syncthreads();
        #pragma unroll 8
        for (int ii = 0; ii < 32; ++ii) {
            const float4 za  = ld4(&zl[ii * 132 + tz * 8]);
            const float4 zb2 = ld4(&zl[ii * 132 + tz * 8 + 4]);
            const float4 ta  = ld4(&t2l[ii * 132 + tn * 8]);
            const float4 tb  = ld4(&t2l[ii * 132 + tn * 8 + 4]);
            const float zr[8] = {za.x, za.y, za.z, za.w, zb2.x, zb2.y, zb2.z, zb2.w};
            const float tr[8] = {ta.x, ta.y, ta.z, ta.w, tb.x, tb.y, tb.z, tb.w};
            #pragma unroll
            for (int a = 0; a < 8; ++a)
                #pragma unroll
                for (int c = 0; c < 8; ++c)
                    acc[a][c] = fmaf(zr[a], tr[c], acc[a][c]);
        }
    }
    float* ob = OUT + (size_t)b * 2097152;
    #pragma unroll
    for (int a = 0; a < 8; ++a) {
        const size_t off = (size_t)(tz * 8 + a) * 16384 + n0 + tn * 8;
        float4 lo = make_float4(acc[a][0], acc[a][1], acc[a][2], acc[a][3]);
        float4 hi = make_float4(acc[a][4], acc[a][5], acc[a][6], acc[a][7]);
        if (!first) {
            const float4 o0 = ld4(&ob[off]);
            const float4 o1 = ld4(&ob[off + 4]);
            lo.x += o0.x; lo.y += o0.y; lo.z += o0.z; lo.w += o0.w;
            hi.x += o1.x; hi.y += o1.y; hi.z += o1.z; hi.w += o1.w;
        }
        *(float4*)&ob[off]     = lo;
        *(float4*)&ob[off + 4] = hi;
    }
}

extern "C" void kernel_launch(void* const* d_in, const int* in_sizes, int n_in,
                              void* d_out, int out_size, void* d_ws, size_t ws_size,
                              hipStream_t stream)
{
    const float* X = (const float*)d_in[0];
    const float* Y = (const float*)d_in[1];
    const float* Z = (const float*)d_in[2];
    const float* W = (const float*)d_in[3];
    float* OUT = (float*)d_out;
    float* T2  = (float*)d_ws;

    // T2 slab = BC * KC * 128*128 * 4 bytes. Shrink KC (512->32), then BC (8->1),
    // until it fits ws_size. Minimum footprint: 1*32*16384*4 = 2.1 MB.
    int BC = 8, KC = 512;
    auto slab = [](int bc, int kc) { return (size_t)bc * kc * 16384u * 4u; };
    while (KC > 32 && slab(BC, KC) > ws_size) KC >>= 1;
    while (BC > 1  && slab(BC, KC) > ws_size) BC >>= 1;

    for (int b0 = 0; b0 < 8; b0 += BC) {
        for (int c = 0; c < 512 / KC; ++c) {
            triaffine_k1<<<dim3(BC, KC), 256, 0, stream>>>(X, Y, W, T2, b0, c * KC, KC);
            triaffine_k2<<<dim3(128, BC), 256, 0, stream>>>(Z, T2, OUT, b0, c * KC, KC, c == 0);
        }
    }
}